// Round 1
// baseline (60.208 us; speedup 1.0000x reference)
//
#include <hip/hip_runtime.h>
#include <math.h>

constexpr int NB    = 128;
constexpr int NPAIR = NB * (NB - 1) / 2;        // 8128
constexpr int NANG  = NB - 2;                   // 126
constexpr int NDIH  = NB - 3;                   // 125
constexpr int ROW   = NPAIR + NANG + 2 * NDIH;  // 8504

__global__ __launch_bounds__(256) void protein_feat_kernel(
        const float* __restrict__ data, float* __restrict__ out) {
    __shared__ float sx[NB], sy[NB], sz[NB];
    const int b = blockIdx.x;
    const float* src = data + (size_t)b * (NB * 3);

    // Stage one protein's 128x3 coords into LDS as SoA.
    for (int t = threadIdx.x; t < NB * 3; t += blockDim.x) {
        float v = src[t];
        int bead = t / 3;
        int c = t - bead * 3;
        if (c == 0)      sx[bead] = v;
        else if (c == 1) sy[bead] = v;
        else             sz[bead] = v;
    }
    __syncthreads();

    float* orow = out + (size_t)b * ROW;

    // ---- Pairwise distances: 8128 values, 4 per thread-iter, float4 stores.
    // Pair ordering: for off in 1..127: for i in 0..(127-off): pair (i, i+off).
    // Invert p -> (off, i) via reversed triangular index:
    //   qq = 8127 - p; row r (size r+1) with r(r+1)/2 <= qq; off = 127-r;
    //   i = r - (qq - r(r+1)/2).
    for (int q = threadIdx.x; q < NPAIR / 4; q += 256) {
        float4 res;
        #pragma unroll
        for (int e = 0; e < 4; ++e) {
            int p  = q * 4 + e;
            int qq = (NPAIR - 1) - p;
            int r  = (int)((sqrtf((float)(8 * qq + 1)) - 1.0f) * 0.5f);
            while (r * (r + 1) / 2 > qq) --r;          // guard fp rounding
            while ((r + 1) * (r + 2) / 2 <= qq) ++r;
            int off = (NB - 1) - r;
            int i   = r - (qq - r * (r + 1) / 2);
            int j   = i + off;
            float dx = sx[j] - sx[i];
            float dy = sy[j] - sy[i];
            float dz = sz[j] - sz[i];
            (&res.x)[e] = sqrtf(dx * dx + dy * dy + dz * dz);
        }
        *reinterpret_cast<float4*>(orow + q * 4) = res;  // 16B-aligned: ROW%4==0
    }

    // ---- Angles (126) + dihedral cos (125) + dihedral sin (125) = 376 values.
    for (int v = threadIdx.x; v < NANG + 2 * NDIH; v += 256) {
        if (v < NANG) {
            int k = v;
            float a0x = sx[k+1]-sx[k],   a0y = sy[k+1]-sy[k],   a0z = sz[k+1]-sz[k];
            float a1x = sx[k+2]-sx[k+1], a1y = sy[k+2]-sy[k+1], a1z = sz[k+2]-sz[k+1];
            float d  = a0x*a1x + a0y*a1y + a0z*a1z;
            float n0 = sqrtf(a0x*a0x + a0y*a0y + a0z*a0z);
            float n1 = sqrtf(a1x*a1x + a1y*a1y + a1z*a1z);
            float c  = d / n0 / n1;
            c = fminf(1.0f, fmaxf(-1.0f, c));   // guard acos domain
            orow[NPAIR + k] = acosf(c);
        } else {
            int k = (v < NANG + NDIH) ? (v - NANG) : (v - NANG - NDIH);
            // adjacent bond vectors e0=adj[k], e1=adj[k+1], e2=adj[k+2]
            float e0x = sx[k+1]-sx[k],   e0y = sy[k+1]-sy[k],   e0z = sz[k+1]-sz[k];
            float e1x = sx[k+2]-sx[k+1], e1y = sy[k+2]-sy[k+1], e1z = sz[k+2]-sz[k+1];
            float e2x = sx[k+3]-sx[k+2], e2y = sy[k+3]-sy[k+2], e2z = sz[k+3]-sz[k+2];
            // c0 = cpa[k] = e0 x e1 ; c1 = cpa[k+1] = e1 x e2
            float c0x = e0y*e1z - e0z*e1y;
            float c0y = e0z*e1x - e0x*e1z;
            float c0z = e0x*e1y - e0y*e1x;
            float c1x = e1y*e2z - e1z*e2y;
            float c1y = e1z*e2x - e1x*e2z;
            float c1z = e1x*e2y - e1y*e2x;
            float nc0 = sqrtf(c0x*c0x + c0y*c0y + c0z*c0z);
            if (v < NANG + NDIH) {
                // dihedral_cos[k] = dot(c0,c1)/|c0|/|c1|
                float d   = c0x*c1x + c0y*c1y + c0z*c1z;
                float nc1 = sqrtf(c1x*c1x + c1y*c1y + c1z*c1z);
                orow[NPAIR + NANG + k] = d / nc0 / nc1;
            } else {
                // plane[k] = cross(cpa[k+1], adj[k+1]) = c1 x e1
                float px = c1y*e1z - c1z*e1y;
                float py = c1z*e1x - c1x*e1z;
                float pz = c1x*e1y - c1y*e1x;
                float d  = c0x*px + c0y*py + c0z*pz;
                float np = sqrtf(px*px + py*py + pz*pz);
                orow[NPAIR + NANG + NDIH + k] = d / nc0 / np;
            }
        }
    }
}

extern "C" void kernel_launch(void* const* d_in, const int* in_sizes, int n_in,
                              void* d_out, int out_size, void* d_ws, size_t ws_size,
                              hipStream_t stream) {
    const float* data = (const float*)d_in[0];
    float* out = (float*)d_out;
    const int batch = in_sizes[0] / (NB * 3);   // 4096
    protein_feat_kernel<<<batch, 256, 0, stream>>>(data, out);
}

// Round 2
// 53.173 us; speedup vs baseline: 1.1323x; 1.1323x over previous
//
#include <hip/hip_runtime.h>
#include <math.h>

constexpr int NB    = 128;
constexpr int NPAIR = NB * (NB - 1) / 2;        // 8128
constexpr int NANG  = NB - 2;                   // 126
constexpr int NDIH  = NB - 3;                   // 125
constexpr int ROW   = NPAIR + NANG + 2 * NDIH;  // 8504

__global__ __launch_bounds__(256) void protein_feat_kernel(
        const float* __restrict__ data, float* __restrict__ out) {
    __shared__ float4 s4[NB];                    // (x,y,z,0) per bead, 16B-aligned
    const int b = blockIdx.x;
    const float* src = data + (size_t)b * (NB * 3);

    // Stage: threads 0..127 each read one bead (contiguous 1.5KB range -> L1/L2).
    if (threadIdx.x < NB) {
        int t = threadIdx.x;
        s4[t] = make_float4(src[3 * t], src[3 * t + 1], src[3 * t + 2], 0.0f);
    }
    __syncthreads();

    float* orow = out + (size_t)b * ROW;

    // ---- Pairwise distances: 8128 values, float4 per thread-iter.
    // Pair ordering: for off in 1..127: for i in 0..(127-off): pair (i, i+off).
    // ONE flat-index inversion per float4; incremental walk for the other 3.
    for (int q = threadIdx.x; q < NPAIR / 4; q += 256) {
        int p  = q * 4;
        int qq = (NPAIR - 1) - p;
        int r  = (int)((__builtin_amdgcn_sqrtf((float)(8 * qq + 1)) - 1.0f) * 0.5f);
        while (r * (r + 1) / 2 > qq) --r;          // fp-rounding guard (rare)
        while ((r + 1) * (r + 2) / 2 <= qq) ++r;
        int off = (NB - 1) - r;
        int i   = r - (qq - r * (r + 1) / 2);

        float4 res;
        #pragma unroll
        for (int e = 0; e < 4; ++e) {
            float4 pi = s4[i];                     // ds_read_b128
            float4 pj = s4[i + off];               // ds_read_b128
            float dx = pj.x - pi.x;
            float dy = pj.y - pi.y;
            float dz = pj.z - pi.z;
            (&res.x)[e] = __builtin_amdgcn_sqrtf(dx * dx + dy * dy + dz * dz);
            ++i;                                   // incremental (off,i) walk
            if (i + off >= NB) { ++off; i = 0; }
        }
        *reinterpret_cast<float4*>(orow + p) = res;  // 16B-aligned: p%4==0, ROW%4==0
    }

    // ---- Angles (126) + dihedral cos (125) + dihedral sin (125).
    for (int v = threadIdx.x; v < NANG + 2 * NDIH; v += 256) {
        if (v < NANG) {
            int k = v;
            float4 p0 = s4[k], p1 = s4[k + 1], p2 = s4[k + 2];
            float a0x = p1.x - p0.x, a0y = p1.y - p0.y, a0z = p1.z - p0.z;
            float a1x = p2.x - p1.x, a1y = p2.y - p1.y, a1z = p2.z - p1.z;
            float d  = a0x * a1x + a0y * a1y + a0z * a1z;
            float r0 = rsqrtf(a0x * a0x + a0y * a0y + a0z * a0z);
            float r1 = rsqrtf(a1x * a1x + a1y * a1y + a1z * a1z);
            float c  = d * r0 * r1;
            c = fminf(1.0f, fmaxf(-1.0f, c));
            orow[NPAIR + k] = acosf(c);
        } else {
            int k = (v < NANG + NDIH) ? (v - NANG) : (v - NANG - NDIH);
            float4 p0 = s4[k], p1 = s4[k + 1], p2 = s4[k + 2], p3 = s4[k + 3];
            float e0x = p1.x - p0.x, e0y = p1.y - p0.y, e0z = p1.z - p0.z;
            float e1x = p2.x - p1.x, e1y = p2.y - p1.y, e1z = p2.z - p1.z;
            float e2x = p3.x - p2.x, e2y = p3.y - p2.y, e2z = p3.z - p2.z;
            // c0 = e0 x e1 ; c1 = e1 x e2
            float c0x = e0y * e1z - e0z * e1y;
            float c0y = e0z * e1x - e0x * e1z;
            float c0z = e0x * e1y - e0y * e1x;
            float c1x = e1y * e2z - e1z * e2y;
            float c1y = e1z * e2x - e1x * e2z;
            float c1z = e1x * e2y - e1y * e2x;
            float rn0 = rsqrtf(c0x * c0x + c0y * c0y + c0z * c0z);
            if (v < NANG + NDIH) {
                float d   = c0x * c1x + c0y * c1y + c0z * c1z;
                float rn1 = rsqrtf(c1x * c1x + c1y * c1y + c1z * c1z);
                orow[NPAIR + NANG + k] = d * rn0 * rn1;
            } else {
                // plane = c1 x e1
                float px = c1y * e1z - c1z * e1y;
                float py = c1z * e1x - c1x * e1z;
                float pz = c1x * e1y - c1y * e1x;
                float d  = c0x * px + c0y * py + c0z * pz;
                float rp = rsqrtf(px * px + py * py + pz * pz);
                orow[NPAIR + NANG + NDIH + k] = d * rn0 * rp;
            }
        }
    }
}

extern "C" void kernel_launch(void* const* d_in, const int* in_sizes, int n_in,
                              void* d_out, int out_size, void* d_ws, size_t ws_size,
                              hipStream_t stream) {
    const float* data = (const float*)d_in[0];
    float* out = (float*)d_out;
    const int batch = in_sizes[0] / (NB * 3);   // 4096
    protein_feat_kernel<<<batch, 256, 0, stream>>>(data, out);
}

// Round 3
// 36.454 us; speedup vs baseline: 1.6516x; 1.4586x over previous
//
#include <hip/hip_runtime.h>
#include <math.h>

constexpr int NB    = 128;
constexpr int NPAIR = NB * (NB - 1) / 2;        // 8128
constexpr int NANG  = NB - 2;                   // 126
constexpr int NDIH  = NB - 3;                   // 125
constexpr int ROW   = NPAIR + NANG + 2 * NDIH;  // 8504

__global__ __launch_bounds__(128) void protein_feat_kernel(
        const float* __restrict__ data, float* __restrict__ out) {
    __shared__ float4 s4[NB];                    // (x,y,z,0) per bead
    const int b = blockIdx.x;
    const int t = threadIdx.x;                   // 0..127 == bead index
    const float* src = data + (size_t)b * (NB * 3);

    s4[t] = make_float4(src[3 * t], src[3 * t + 1], src[3 * t + 2], 0.0f);
    __syncthreads();

    float* orow = out + (size_t)b * ROW;

    // ---- Pairwise distances, offset-major: lane t owns bead i=t (pi in regs).
    // For each off: lanes read s4[t+off] (16B stride -> conflict-free b128),
    // store out[rowbase + t] (coalesced, rowbase uniform).
    const float4 pi = s4[t];
    int rowbase = 0;
    #pragma unroll 4
    for (int off = 1; off < NB; ++off) {
        if (t < NB - off) {
            float4 pj = s4[t + off];
            float dx = pj.x - pi.x;
            float dy = pj.y - pi.y;
            float dz = pj.z - pi.z;
            orow[rowbase + t] = __builtin_amdgcn_sqrtf(dx * dx + dy * dy + dz * dz);
        }
        rowbase += NB - off;
    }

    // ---- Angles (126) + dihedral cos (125) + dihedral sin (125).
    for (int v = t; v < NANG + 2 * NDIH; v += 128) {
        if (v < NANG) {
            int k = v;
            float4 p0 = s4[k], p1 = s4[k + 1], p2 = s4[k + 2];
            float a0x = p1.x - p0.x, a0y = p1.y - p0.y, a0z = p1.z - p0.z;
            float a1x = p2.x - p1.x, a1y = p2.y - p1.y, a1z = p2.z - p1.z;
            float d  = a0x * a1x + a0y * a1y + a0z * a1z;
            float r0 = rsqrtf(a0x * a0x + a0y * a0y + a0z * a0z);
            float r1 = rsqrtf(a1x * a1x + a1y * a1y + a1z * a1z);
            float c  = d * r0 * r1;
            c = fminf(1.0f, fmaxf(-1.0f, c));
            orow[NPAIR + k] = acosf(c);
        } else {
            int k = (v < NANG + NDIH) ? (v - NANG) : (v - NANG - NDIH);
            float4 p0 = s4[k], p1 = s4[k + 1], p2 = s4[k + 2], p3 = s4[k + 3];
            float e0x = p1.x - p0.x, e0y = p1.y - p0.y, e0z = p1.z - p0.z;
            float e1x = p2.x - p1.x, e1y = p2.y - p1.y, e1z = p2.z - p1.z;
            float e2x = p3.x - p2.x, e2y = p3.y - p2.y, e2z = p3.z - p2.z;
            // c0 = e0 x e1 ; c1 = e1 x e2
            float c0x = e0y * e1z - e0z * e1y;
            float c0y = e0z * e1x - e0x * e1z;
            float c0z = e0x * e1y - e0y * e1x;
            float c1x = e1y * e2z - e1z * e2y;
            float c1y = e1z * e2x - e1x * e2z;
            float c1z = e1x * e2y - e1y * e2x;
            float rn0 = rsqrtf(c0x * c0x + c0y * c0y + c0z * c0z);
            if (v < NANG + NDIH) {
                float d   = c0x * c1x + c0y * c1y + c0z * c1z;
                float rn1 = rsqrtf(c1x * c1x + c1y * c1y + c1z * c1z);
                orow[NPAIR + NANG + k] = d * rn0 * rn1;
            } else {
                // plane = c1 x e1
                float px = c1y * e1z - c1z * e1y;
                float py = c1z * e1x - c1x * e1z;
                float pz = c1x * e1y - c1y * e1x;
                float d  = c0x * px + c0y * py + c0z * pz;
                float rp = rsqrtf(px * px + py * py + pz * pz);
                orow[NPAIR + NANG + NDIH + k] = d * rn0 * rp;
            }
        }
    }
}

extern "C" void kernel_launch(void* const* d_in, const int* in_sizes, int n_in,
                              void* d_out, int out_size, void* d_ws, size_t ws_size,
                              hipStream_t stream) {
    const float* data = (const float*)d_in[0];
    float* out = (float*)d_out;
    const int batch = in_sizes[0] / (NB * 3);   // 4096
    protein_feat_kernel<<<batch, 128, 0, stream>>>(data, out);
}

// Round 4
// 33.531 us; speedup vs baseline: 1.7956x; 1.0872x over previous
//
#include <hip/hip_runtime.h>
#include <math.h>

constexpr int NB    = 128;
constexpr int NPAIR = NB * (NB - 1) / 2;        // 8128
constexpr int NANG  = NB - 2;                   // 126
constexpr int NDIH  = NB - 3;                   // 125
constexpr int ROW   = NPAIR + NANG + 2 * NDIH;  // 8504

__global__ __launch_bounds__(128) void protein_feat_kernel(
        const float* __restrict__ data, float* __restrict__ out) {
    __shared__ float4 s4[NB];                    // (x,y,z,0) per bead
    const int b = blockIdx.x;
    const int t = threadIdx.x;                   // 0..127 == bead index
    const float* src = data + (size_t)b * (NB * 3);

    s4[t] = make_float4(src[3 * t], src[3 * t + 1], src[3 * t + 2], 0.0f);
    __syncthreads();

    float* orow = out + (size_t)b * ROW;

    // Register band: lane t holds beads t, t-1, t-2, t-3 (xyz only).
    float px[4], py[4], pz[4];
    #pragma unroll
    for (int k = 0; k < 4; ++k) {
        int idx = t - k; if (idx < 0) idx = 0;   // clamped; values unused when masked
        float4 v = s4[idx];
        px[k] = v.x; py[k] = v.y; pz[k] = v.z;
    }

    // ---- Pairwise distances, 4 rows per LDS read.
    // One ds_read_b128 pj=s4[t+off] -> pairs (t-k, t+off), row off+k, pos t-k.
    // All 4 stores stride-1 across lanes (coalesced). 32 iterations.
    int base = 0;                                // B(off), B(1)=0
    for (int off = 1; off < NB; off += 4) {
        const int len = NB - off;                // row `off` length
        int bk[4];
        bk[0] = base;
        bk[1] = bk[0] + len;
        bk[2] = bk[1] + len - 1;
        bk[3] = bk[2] + len - 2;
        base  = bk[3] + len - 3;                 // B(off+4)
        if (t < len) {                           // j = t+off <= 127 (wave 1 execz-skips off>63)
            float4 pj = s4[t + off];
            #pragma unroll
            for (int k = 0; k < 4; ++k) {
                float dx = pj.x - px[k];
                float dy = pj.y - py[k];
                float dz = pj.z - pz[k];
                float d  = __builtin_amdgcn_sqrtf(dx * dx + dy * dy + dz * dz);
                if (t >= k)                       // i = t-k >= 0 (k=0 folds away)
                    orow[bk[k] + t - k] = d;
            }
        }
    }

    // ---- Angles (126) + dihedral cos (125) + dihedral sin (125).
    for (int v = t; v < NANG + 2 * NDIH; v += 128) {
        if (v < NANG) {
            int k = v;
            float4 p0 = s4[k], p1 = s4[k + 1], p2 = s4[k + 2];
            float a0x = p1.x - p0.x, a0y = p1.y - p0.y, a0z = p1.z - p0.z;
            float a1x = p2.x - p1.x, a1y = p2.y - p1.y, a1z = p2.z - p1.z;
            float d  = a0x * a1x + a0y * a1y + a0z * a1z;
            float r0 = rsqrtf(a0x * a0x + a0y * a0y + a0z * a0z);
            float r1 = rsqrtf(a1x * a1x + a1y * a1y + a1z * a1z);
            float c  = d * r0 * r1;
            c = fminf(1.0f, fmaxf(-1.0f, c));
            orow[NPAIR + k] = acosf(c);
        } else {
            int k = (v < NANG + NDIH) ? (v - NANG) : (v - NANG - NDIH);
            float4 p0 = s4[k], p1 = s4[k + 1], p2 = s4[k + 2], p3 = s4[k + 3];
            float e0x = p1.x - p0.x, e0y = p1.y - p0.y, e0z = p1.z - p0.z;
            float e1x = p2.x - p1.x, e1y = p2.y - p1.y, e1z = p2.z - p1.z;
            float e2x = p3.x - p2.x, e2y = p3.y - p2.y, e2z = p3.z - p2.z;
            // c0 = e0 x e1 ; c1 = e1 x e2
            float c0x = e0y * e1z - e0z * e1y;
            float c0y = e0z * e1x - e0x * e1z;
            float c0z = e0x * e1y - e0y * e1x;
            float c1x = e1y * e2z - e1z * e2y;
            float c1y = e1z * e2x - e1x * e2z;
            float c1z = e1x * e2y - e1y * e2x;
            float rn0 = rsqrtf(c0x * c0x + c0y * c0y + c0z * c0z);
            if (v < NANG + NDIH) {
                float d   = c0x * c1x + c0y * c1y + c0z * c1z;
                float rn1 = rsqrtf(c1x * c1x + c1y * c1y + c1z * c1z);
                orow[NPAIR + NANG + k] = d * rn0 * rn1;
            } else {
                // plane = c1 x e1
                float px_ = c1y * e1z - c1z * e1y;
                float py_ = c1z * e1x - c1x * e1z;
                float pz_ = c1x * e1y - c1y * e1x;
                float d  = c0x * px_ + c0y * py_ + c0z * pz_;
                float rp = rsqrtf(px_ * px_ + py_ * py_ + pz_ * pz_);
                orow[NPAIR + NANG + NDIH + k] = d * rn0 * rp;
            }
        }
    }
}

extern "C" void kernel_launch(void* const* d_in, const int* in_sizes, int n_in,
                              void* d_out, int out_size, void* d_ws, size_t ws_size,
                              hipStream_t stream) {
    const float* data = (const float*)d_in[0];
    float* out = (float*)d_out;
    const int batch = in_sizes[0] / (NB * 3);   // 4096
    protein_feat_kernel<<<batch, 128, 0, stream>>>(data, out);
}